// Round 6
// baseline (132.772 us; speedup 1.0000x reference)
//
#include <hip/hip_runtime.h>

// B=2, N_mm=64, N_a=N_v=256, DIM=512, H=8, hd=64, scale=1/8.
// Factorized: softmax over (i,j) grid with logits Av_i+Aa_j, values vv_i+va_j
// = SUM of two independently-normalized 256-key attentions:
//   out = (Σ_i softmax_i(Av) vv_i) + (Σ_j softmax_j(Aa) va_j).
//
// SINGLE persistent kernel, 256 blocks x 256 threads, 3 phases separated by
// device-scope spin barriers (counters in d_ws, memset to 0 per launch):
//   A: q/pv/pa projections (272 64x64 MFMA tiles; 16 blocks run 2 tiles)
//   B: 128 attention tasks (bh x qtile x side), per-side normalized
//   C: 16 out-projection tiles, A-operand = hv+ha summed in staging
//
// Workspace (f16 units), per-(b,h) slab layouts for attn:
//   Q16 : [b][h][n(64)][d(64)]          q*scale
//   K16 : [side][b][h][key(256)][d(64)]
//   VT16: [side][b][h][d(64)][key(256)]
//   hv/ha: two f32 [128][512] per-side outputs at OHOUT16.
//   barrier ints at byte offset 4 MiB.

#define OQ16   0
#define OK16   65536
#define OVT16  589824
#define SIDESZ 262144
#define OHOUT16 1114112
#define BAR_BYTE_OFF (4u << 20)
#define NBLK 256

typedef _Float16 f16x8 __attribute__((ext_vector_type(8)));
typedef _Float16 f16x4 __attribute__((ext_vector_type(4)));
typedef float f32x4 __attribute__((ext_vector_type(4)));

// ---- device-scope grid barrier (one counter per barrier, pre-zeroed) ------
__device__ __forceinline__ void gbar(int* cnt)
{
  __syncthreads();
  if (threadIdx.x == 0) {
    __threadfence();   // release: prior writes visible device-wide
    __hip_atomic_fetch_add(cnt, 1, __ATOMIC_RELEASE, __HIP_MEMORY_SCOPE_AGENT);
    while (__hip_atomic_load(cnt, __ATOMIC_ACQUIRE,
                             __HIP_MEMORY_SCOPE_AGENT) < NBLK)
      __builtin_amdgcn_s_sleep(1);
    __threadfence();   // acquire: invalidate stale cached lines
  }
  __syncthreads();
}

// ---- fp32 -> swizzled f16 LDS staging (16B-chunk XOR swizzle) -------------
__device__ __forceinline__ void stage_tile_f16(
    const float* __restrict__ g, const float* __restrict__ g2, int ld,
    int base, int k0, _Float16* __restrict__ lds, int sr, int sq)
{
  const float* p = &g[(size_t)(base + sr) * ld + k0 + sq * 16];
  float4 v0 = *reinterpret_cast<const float4*>(p);
  float4 v1 = *reinterpret_cast<const float4*>(p + 4);
  float4 v2 = *reinterpret_cast<const float4*>(p + 8);
  float4 v3 = *reinterpret_cast<const float4*>(p + 12);
  if (g2) {
    const float* p2 = &g2[(size_t)(base + sr) * ld + k0 + sq * 16];
    float4 u0 = *reinterpret_cast<const float4*>(p2);
    float4 u1 = *reinterpret_cast<const float4*>(p2 + 4);
    float4 u2 = *reinterpret_cast<const float4*>(p2 + 8);
    float4 u3 = *reinterpret_cast<const float4*>(p2 + 12);
    v0.x += u0.x; v0.y += u0.y; v0.z += u0.z; v0.w += u0.w;
    v1.x += u1.x; v1.y += u1.y; v1.z += u1.z; v1.w += u1.w;
    v2.x += u2.x; v2.y += u2.y; v2.z += u2.z; v2.w += u2.w;
    v3.x += u3.x; v3.y += u3.y; v3.z += u3.z; v3.w += u3.w;
  }
  f16x8 h0 = {(_Float16)v0.x, (_Float16)v0.y, (_Float16)v0.z, (_Float16)v0.w,
              (_Float16)v1.x, (_Float16)v1.y, (_Float16)v1.z, (_Float16)v1.w};
  f16x8 h1 = {(_Float16)v2.x, (_Float16)v2.y, (_Float16)v2.z, (_Float16)v2.w,
              (_Float16)v3.x, (_Float16)v3.y, (_Float16)v3.z, (_Float16)v3.w};
  int c0 = (sq * 2) ^ (sr & 7);
  int c1 = (sq * 2 + 1) ^ (sr & 7);
  *reinterpret_cast<f16x8*>(&lds[sr * 64 + c0 * 8]) = h0;
  *reinterpret_cast<f16x8*>(&lds[sr * 64 + c1 * 8]) = h1;
}

// ---- MFMA f16 64x64 GEMM tile: C = A[.,512] @ W[.,512]^T ------------------
// MODE 0: q -> f16*1/8 Q16 slabs; MODE 1: kv -> K16 / transposed VT16 slabs;
// MODE 2: f32 + bias (A = A + A2 summed in staging).
template <int MODE>
__device__ void gemm_task(
    const float* __restrict__ A, const float* __restrict__ A2, int lda,
    const float* __restrict__ W, int ldw,
    int bm, int bn, int side,
    _Float16* __restrict__ ws16,
    float* __restrict__ Cf, int ldc, const float* __restrict__ bias,
    _Float16* __restrict__ As, _Float16* __restrict__ Ws)
{
  const int tid = threadIdx.x;
  const int lane = tid & 63;
  const int w = tid >> 6;
  const int wm = w >> 1, wn = w & 1;
  const int sr = tid >> 2;
  const int sq = tid & 3;

  f32x4 acc[2][2] = {};
  const int cl = lane & 15;
  const int kg = lane >> 4;

  for (int k0 = 0; k0 < 512; k0 += 64) {
    __syncthreads();
    stage_tile_f16(A, A2, lda, bm, k0, As, sr, sq);
    stage_tile_f16(W, nullptr, ldw, bn, k0, Ws, sr, sq);
    __syncthreads();
    #pragma unroll
    for (int ks = 0; ks < 2; ++ks) {
      f16x8 af[2], bf[2];
      #pragma unroll
      for (int mi = 0; mi < 2; ++mi) {
        int row = wm * 32 + mi * 16 + cl;
        int ch = (ks * 4 + kg) ^ (row & 7);
        af[mi] = *reinterpret_cast<const f16x8*>(&As[row * 64 + ch * 8]);
      }
      #pragma unroll
      for (int ni = 0; ni < 2; ++ni) {
        int col = wn * 32 + ni * 16 + cl;
        int ch = (ks * 4 + kg) ^ (col & 7);
        bf[ni] = *reinterpret_cast<const f16x8*>(&Ws[col * 64 + ch * 8]);
      }
      #pragma unroll
      for (int mi = 0; mi < 2; ++mi)
        #pragma unroll
        for (int ni = 0; ni < 2; ++ni)
          acc[mi][ni] = __builtin_amdgcn_mfma_f32_16x16x32_f16(
              af[mi], bf[ni], acc[mi][ni], 0, 0, 0);
    }
  }

  #pragma unroll
  for (int mi = 0; mi < 2; ++mi) {
    #pragma unroll
    for (int ni = 0; ni < 2; ++ni) {
      int row0 = bm + wm * 32 + mi * 16 + kg * 4;
      int col = bn + wn * 32 + ni * 16 + cl;
      if (MODE == 0) {
        int b = row0 >> 6, n = row0 & 63, h = col >> 6, d = col & 63;
        _Float16* dst = ws16 + OQ16 + (((size_t)b * 8 + h) * 64 + n) * 64 + d;
        #pragma unroll
        for (int r = 0; r < 4; ++r)
          dst[(size_t)r * 64] = (_Float16)(acc[mi][ni][r] * 0.125f);
      } else if (MODE == 1) {
        int b = row0 >> 8, key = row0 & 255;
        if (col < 512) {
          int h = col >> 6, d = col & 63;
          _Float16* dst = ws16 + OK16 + (size_t)side * SIDESZ +
                          (((size_t)b * 8 + h) * 256 + key) * 64 + d;
          #pragma unroll
          for (int r = 0; r < 4; ++r)
            dst[(size_t)r * 64] = (_Float16)acc[mi][ni][r];
        } else {
          int dp = col - 512;
          int h = dp >> 6, d = dp & 63;
          _Float16* dst = ws16 + OVT16 + (size_t)side * SIDESZ +
                          (((size_t)b * 8 + h) * 64 + d) * 256 + key;
          f16x4 v = {(_Float16)acc[mi][ni][0], (_Float16)acc[mi][ni][1],
                     (_Float16)acc[mi][ni][2], (_Float16)acc[mi][ni][3]};
          *reinterpret_cast<f16x4*>(dst) = v;
        }
      } else {
        float bv = bias ? bias[col] : 0.f;
        #pragma unroll
        for (int r = 0; r < 4; ++r)
          Cf[(size_t)(row0 + r) * ldc + col] = acc[mi][ni][r] + bv;
      }
    }
  }
}

// ---- attention task: x = (bh<<3)|(qtl<<1)|side, per-side normalized -------
__device__ void attn_task(
    const _Float16* __restrict__ ws16, float* __restrict__ hv,
    float* __restrict__ ha, int x, _Float16* __restrict__ smem)
{
  _Float16* P = smem;                          // [16][256] swizzled
  float* m_s = (float*)(smem + 4096);          // [4][16]
  float* l_s = m_s + 64;                       // [4][16]

  const int side = x & 1;
  const int qtl = (x >> 1) & 3;
  const int bh = x >> 3;
  const int b = bh >> 3;

  const int tid = threadIdx.x;
  const int w = tid >> 6;
  const int lane = tid & 63;
  const int l15 = lane & 15;
  const int g = lane >> 4;

  const _Float16* slabQ = ws16 + OQ16 + (size_t)bh * 4096;
  const _Float16* slabK = ws16 + OK16 + (size_t)side * SIDESZ + (size_t)bh * 16384;
  const _Float16* slabV = ws16 + OVT16 + (size_t)side * SIDESZ + (size_t)bh * 16384;

  f16x8 qb[2];
  #pragma unroll
  for (int ks = 0; ks < 2; ++ks)
    qb[ks] = *reinterpret_cast<const f16x8*>(
        &slabQ[(size_t)(qtl * 16 + l15) * 64 + ks * 32 + g * 8]);

  // S^T for this wave's 64 keys
  f32x4 st[4] = {};
  #pragma unroll
  for (int f = 0; f < 4; ++f) {
    #pragma unroll
    for (int ks = 0; ks < 2; ++ks) {
      f16x8 af = *reinterpret_cast<const f16x8*>(
          &slabK[(size_t)(w * 64 + f * 16 + l15) * 64 + ks * 32 + g * 8]);
      st[f] = __builtin_amdgcn_mfma_f32_16x16x32_f16(af, qb[ks], st[f], 0, 0, 0);
    }
  }

  float m = st[0][0];
  #pragma unroll
  for (int f = 0; f < 4; ++f)
    #pragma unroll
    for (int r = 0; r < 4; ++r) m = fmaxf(m, st[f][r]);
  m = fmaxf(m, __shfl_xor(m, 16));
  m = fmaxf(m, __shfl_xor(m, 32));
  if (g == 0) m_s[w * 16 + l15] = m;
  __syncthreads();

  float M = fmaxf(fmaxf(m_s[l15], m_s[16 + l15]),
                  fmaxf(m_s[32 + l15], m_s[48 + l15]));
  float lsum = 0.f;
  #pragma unroll
  for (int f = 0; f < 4; ++f)
    #pragma unroll
    for (int r = 0; r < 4; ++r) {
      float e = __expf(st[f][r] - M);
      st[f][r] = e;
      lsum += e;
    }
  lsum += __shfl_xor(lsum, 16);
  lsum += __shfl_xor(lsum, 32);
  if (g == 0) l_s[w * 16 + l15] = lsum;

  #pragma unroll
  for (int f = 0; f < 4; ++f) {
    f16x4 pk = {(_Float16)st[f][0], (_Float16)st[f][1],
                (_Float16)st[f][2], (_Float16)st[f][3]};
    int chunk = w * 8 + 2 * f + (g >> 1);
    int swz = chunk ^ (l15 & 7);
    *reinterpret_cast<f16x4*>(&P[l15 * 256 + swz * 8 + (g & 1) * 4]) = pk;
  }
  __syncthreads();

  f32x4 L4 = {};
  #pragma unroll
  for (int w2 = 0; w2 < 4; ++w2)
    L4 += *reinterpret_cast<const f32x4*>(&l_s[w2 * 16 + g * 4]);

  // PV: wave owns d-frag w, all 256 keys
  f32x4 oc = {};
  #pragma unroll
  for (int ks = 0; ks < 8; ++ks) {
    f16x8 pa = *reinterpret_cast<const f16x8*>(
        &P[l15 * 256 + ((4 * ks + g) ^ (l15 & 7)) * 8]);
    f16x8 vb = *reinterpret_cast<const f16x8*>(
        &slabV[(size_t)(w * 16 + l15) * 256 + ks * 32 + g * 8]);
    oc = __builtin_amdgcn_mfma_f32_16x16x32_f16(pa, vb, oc, 0, 0, 0);
  }

  float* houtS = side ? ha : hv;
  const int h = bh & 7;
  #pragma unroll
  for (int r = 0; r < 4; ++r)
    houtS[(size_t)(b * 64 + qtl * 16 + 4 * g + r) * 512 +
          h * 64 + w * 16 + l15] = oc[r] * (1.0f / L4[r]);
  __syncthreads();   // P reuse safety before leaving task
}

// ---- the single fused kernel ----------------------------------------------
__global__ __launch_bounds__(256) void fused_all_kernel(
    const float* __restrict__ xmm, const float* __restrict__ xa,
    const float* __restrict__ xv, const float* __restrict__ Wq,
    const float* __restrict__ Wkv, const float* __restrict__ Wproj,
    const float* __restrict__ bproj, float* __restrict__ out,
    _Float16* __restrict__ ws16, int* __restrict__ bar)
{
  __shared__ __align__(16) _Float16 smem[8448];   // 16.5 KB
  _Float16* As = smem;
  _Float16* Ws = smem + 4096;
  const int bid = blockIdx.x;

  // ---- phase A: projections (272 tiles)
  {
    int t = bid;
    if (t < 16) {
      gemm_task<0>(xmm, nullptr, 512, Wq, 512, (t >> 3) * 64, (t & 7) * 64, 0,
                   ws16, nullptr, 0, nullptr, As, Ws);
    } else if (t < 144) {
      int u = t - 16;
      gemm_task<1>(xv, nullptr, 512, Wkv, 1024, (u >> 4) * 64, (u & 15) * 64,
                   0, ws16, nullptr, 0, nullptr, As, Ws);
    } else {
      int u = t - 144;
      gemm_task<1>(xa, nullptr, 512, Wkv + 512, 1024, (u >> 4) * 64,
                   (u & 15) * 64, 1, ws16, nullptr, 0, nullptr, As, Ws);
    }
    if (bid >= 240) {                       // pa tiles 112..127 (second task)
      int u = bid - 240 + 112;
      gemm_task<1>(xa, nullptr, 512, Wkv + 512, 1024, (u >> 4) * 64,
                   (u & 15) * 64, 1, ws16, nullptr, 0, nullptr, As, Ws);
    }
  }
  gbar(bar);

  // ---- phase B: attention (128 tasks)
  float* hv = (float*)(ws16 + OHOUT16);
  float* ha = hv + 65536;
  if (bid < 128) attn_task(ws16, hv, ha, bid, smem);
  gbar(bar + 1);

  // ---- phase C: out-projection (16 tiles), A = hv + ha
  if (bid >= 128 && bid < 144) {
    int t = bid - 128;
    gemm_task<2>(hv, ha, 512, Wproj, 512, (t >> 3) * 64, (t & 7) * 64, 0,
                 nullptr, out, 512, bproj, As, Ws);
  }
}

extern "C" void kernel_launch(void* const* d_in, const int* in_sizes, int n_in,
                              void* d_out, int out_size, void* d_ws, size_t ws_size,
                              hipStream_t stream) {
  const float* xmm   = (const float*)d_in[0];  // [2,64,512]
  const float* xa    = (const float*)d_in[1];  // [2,256,512]
  const float* xv    = (const float*)d_in[2];  // [2,256,512]
  const float* Wq    = (const float*)d_in[3];  // [512,512]
  const float* Wkv   = (const float*)d_in[4];  // [1024,1024]
  const float* Wproj = (const float*)d_in[5];  // [512,512]
  const float* bproj = (const float*)d_in[6];  // [512]
  float* out = (float*)d_out;                  // [2,64,512]
  _Float16* ws16 = (_Float16*)d_ws;
  int* bar = (int*)((char*)d_ws + BAR_BYTE_OFF);

  hipMemsetAsync(bar, 0, 16, stream);          // zero barrier counters
  fused_all_kernel<<<NBLK, 256, 0, stream>>>(
      xmm, xa, xv, Wq, Wkv, Wproj, bproj, out, ws16, bar);
}

// Round 7
// 34.557 us; speedup vs baseline: 3.8421x; 3.8421x over previous
//
#include <hip/hip_runtime.h>

// B=2, N_mm=64, N_a=N_v=256, DIM=512, H=8, hd=64, scale=1/8.
// Factorized: softmax over (i,j) grid with logits Av_i+Aa_j, values vv_i+va_j
// = SUM of two independently-normalized 256-key attentions:
//   out = (Σ_i softmax_i(Av) vv_i) + (Σ_j softmax_j(Aa) va_j).
//
// 3 kernels (graph-boundary sync; spin barriers were 60µs/each — removed):
//   K1: q/pv/pa projections -> f16 per-(b,h) slabs
//   K2: attention, all operands STAGED TO LDS coalesced (the R2-R5 attn was
//       bound by scattered 16B global fragment loads serialized vs MFMA)
//   K3: out-projection, A = hv+ha summed in staging
//
// Workspace (f16 units):
//   Q16 : [b][h][n(64)][d(64)]          q*scale
//   K16 : [side][b][h][key(256)][d(64)]
//   VT16: [side][b][h][d(64)][key(256)]
//   hv/ha: two f32 [128][512] per-side outputs at OHOUT16.

#define OQ16   0
#define OK16   65536
#define OVT16  589824
#define SIDESZ 262144
#define OHOUT16 1114112

typedef _Float16 f16x8 __attribute__((ext_vector_type(8)));
typedef _Float16 f16x4 __attribute__((ext_vector_type(4)));
typedef float f32x4 __attribute__((ext_vector_type(4)));

// ---- fp32 -> swizzled f16 LDS staging (16B-chunk XOR swizzle) -------------
__device__ __forceinline__ void stage_tile_f16(
    const float* __restrict__ g, const float* __restrict__ g2, int ld,
    int base, int k0, _Float16* __restrict__ lds, int sr, int sq)
{
  const float* p = &g[(size_t)(base + sr) * ld + k0 + sq * 16];
  float4 v0 = *reinterpret_cast<const float4*>(p);
  float4 v1 = *reinterpret_cast<const float4*>(p + 4);
  float4 v2 = *reinterpret_cast<const float4*>(p + 8);
  float4 v3 = *reinterpret_cast<const float4*>(p + 12);
  if (g2) {
    const float* p2 = &g2[(size_t)(base + sr) * ld + k0 + sq * 16];
    float4 u0 = *reinterpret_cast<const float4*>(p2);
    float4 u1 = *reinterpret_cast<const float4*>(p2 + 4);
    float4 u2 = *reinterpret_cast<const float4*>(p2 + 8);
    float4 u3 = *reinterpret_cast<const float4*>(p2 + 12);
    v0.x += u0.x; v0.y += u0.y; v0.z += u0.z; v0.w += u0.w;
    v1.x += u1.x; v1.y += u1.y; v1.z += u1.z; v1.w += u1.w;
    v2.x += u2.x; v2.y += u2.y; v2.z += u2.z; v2.w += u2.w;
    v3.x += u3.x; v3.y += u3.y; v3.z += u3.z; v3.w += u3.w;
  }
  f16x8 h0 = {(_Float16)v0.x, (_Float16)v0.y, (_Float16)v0.z, (_Float16)v0.w,
              (_Float16)v1.x, (_Float16)v1.y, (_Float16)v1.z, (_Float16)v1.w};
  f16x8 h1 = {(_Float16)v2.x, (_Float16)v2.y, (_Float16)v2.z, (_Float16)v2.w,
              (_Float16)v3.x, (_Float16)v3.y, (_Float16)v3.z, (_Float16)v3.w};
  int c0 = (sq * 2) ^ (sr & 7);
  int c1 = (sq * 2 + 1) ^ (sr & 7);
  *reinterpret_cast<f16x8*>(&lds[sr * 64 + c0 * 8]) = h0;
  *reinterpret_cast<f16x8*>(&lds[sr * 64 + c1 * 8]) = h1;
}

// ---- MFMA f16 64x64 GEMM tile: C = A[.,512] @ W[.,512]^T ------------------
template <int MODE>
__device__ __forceinline__ void mfma_gemm64(
    const float* __restrict__ A, const float* __restrict__ A2, int lda,
    const float* __restrict__ W, int ldw,
    int bm, int bn, int side,
    _Float16* __restrict__ ws16,
    float* __restrict__ Cf, int ldc, const float* __restrict__ bias)
{
  __shared__ _Float16 As[64 * 64];   // 8 KB
  __shared__ _Float16 Ws[64 * 64];   // 8 KB
  const int tid = threadIdx.x;
  const int lane = tid & 63;
  const int w = tid >> 6;
  const int wm = w >> 1, wn = w & 1;
  const int sr = tid >> 2;
  const int sq = tid & 3;

  f32x4 acc[2][2] = {};
  const int cl = lane & 15;
  const int kg = lane >> 4;

  for (int k0 = 0; k0 < 512; k0 += 64) {
    __syncthreads();
    stage_tile_f16(A, A2, lda, bm, k0, As, sr, sq);
    stage_tile_f16(W, nullptr, ldw, bn, k0, Ws, sr, sq);
    __syncthreads();
    #pragma unroll
    for (int ks = 0; ks < 2; ++ks) {
      f16x8 af[2], bf[2];
      #pragma unroll
      for (int mi = 0; mi < 2; ++mi) {
        int row = wm * 32 + mi * 16 + cl;
        int ch = (ks * 4 + kg) ^ (row & 7);
        af[mi] = *reinterpret_cast<const f16x8*>(&As[row * 64 + ch * 8]);
      }
      #pragma unroll
      for (int ni = 0; ni < 2; ++ni) {
        int col = wn * 32 + ni * 16 + cl;
        int ch = (ks * 4 + kg) ^ (col & 7);
        bf[ni] = *reinterpret_cast<const f16x8*>(&Ws[col * 64 + ch * 8]);
      }
      #pragma unroll
      for (int mi = 0; mi < 2; ++mi)
        #pragma unroll
        for (int ni = 0; ni < 2; ++ni)
          acc[mi][ni] = __builtin_amdgcn_mfma_f32_16x16x32_f16(
              af[mi], bf[ni], acc[mi][ni], 0, 0, 0);
    }
  }

  #pragma unroll
  for (int mi = 0; mi < 2; ++mi) {
    #pragma unroll
    for (int ni = 0; ni < 2; ++ni) {
      int row0 = bm + wm * 32 + mi * 16 + kg * 4;
      int col = bn + wn * 32 + ni * 16 + cl;
      if (MODE == 0) {
        int b = row0 >> 6, n = row0 & 63, h = col >> 6, d = col & 63;
        _Float16* dst = ws16 + OQ16 + (((size_t)b * 8 + h) * 64 + n) * 64 + d;
        #pragma unroll
        for (int r = 0; r < 4; ++r)
          dst[(size_t)r * 64] = (_Float16)(acc[mi][ni][r] * 0.125f);
      } else if (MODE == 1) {
        int b = row0 >> 8, key = row0 & 255;
        if (col < 512) {
          int h = col >> 6, d = col & 63;
          _Float16* dst = ws16 + OK16 + (size_t)side * SIDESZ +
                          (((size_t)b * 8 + h) * 256 + key) * 64 + d;
          #pragma unroll
          for (int r = 0; r < 4; ++r)
            dst[(size_t)r * 64] = (_Float16)acc[mi][ni][r];
        } else {
          int dp = col - 512;
          int h = dp >> 6, d = dp & 63;
          _Float16* dst = ws16 + OVT16 + (size_t)side * SIDESZ +
                          (((size_t)b * 8 + h) * 64 + d) * 256 + key;
          f16x4 v = {(_Float16)acc[mi][ni][0], (_Float16)acc[mi][ni][1],
                     (_Float16)acc[mi][ni][2], (_Float16)acc[mi][ni][3]};
          *reinterpret_cast<f16x4*>(dst) = v;
        }
      } else {
        float bv = bias ? bias[col] : 0.f;
        #pragma unroll
        for (int r = 0; r < 4; ++r)
          Cf[(size_t)(row0 + r) * ldc + col] = acc[mi][ni][r] + bv;
      }
    }
  }
}

// K1: fused q / pv / pa projections. 272 blocks x 256 threads.
__global__ __launch_bounds__(256) void fused_proj_kernel(
    const float* __restrict__ xmm, const float* __restrict__ xa,
    const float* __restrict__ xv, const float* __restrict__ Wq,
    const float* __restrict__ Wkv, _Float16* __restrict__ ws16)
{
  const int id = blockIdx.x;
  if (id < 16) {
    mfma_gemm64<0>(xmm, nullptr, 512, Wq, 512, (id >> 3) * 64, (id & 7) * 64,
                   0, ws16, nullptr, 0, nullptr);
  } else if (id < 144) {
    int t = id - 16;
    mfma_gemm64<1>(xv, nullptr, 512, Wkv, 1024, (t >> 4) * 64, (t & 15) * 64,
                   0, ws16, nullptr, 0, nullptr);
  } else {
    int t = id - 144;
    mfma_gemm64<1>(xa, nullptr, 512, Wkv + 512, 1024, (t >> 4) * 64,
                   (t & 15) * 64, 1, ws16, nullptr, 0, nullptr);
  }
}

// K3: out = (hv + ha) @ Wproj.T + bproj. 16 blocks x 256 threads.
__global__ __launch_bounds__(256) void proj_out_kernel(
    const _Float16* __restrict__ ws16, const float* __restrict__ Wproj,
    const float* __restrict__ bproj, float* __restrict__ out)
{
  const float* hv = (const float*)(ws16 + OHOUT16);
  const float* ha = hv + 65536;
  mfma_gemm64<2>(hv, ha, 512, Wproj, 512,
                 (int)(blockIdx.x >> 3) * 64, (int)(blockIdx.x & 7) * 64, 0,
                 nullptr, out, 512, bproj);
}

// ---------------------------------------------------------------------------
// K2: attention, one block per (bh, side) = 32 blocks x 512 threads (8 waves).
// ALL MFMA operands staged to LDS with coalesced 16B-chunk copies + XOR
// chunk swizzle (conflict-free ds_read_b128). Per block:
//   QK^T: wave w owns keys w*32..w*32+31, computes S^T for all 64 q.
//   softmax: cross-wave (m,l) merge via LDS; P (e^{s-M}) -> swizzled LDS f16.
//   PV: wave w owns (qf = w&3, d-frags 2*(w>>2)+{0,1}); per-side normalized
//       output to hv/ha (sides summed exactly in K3).
// ---------------------------------------------------------------------------
__global__ __launch_bounds__(512) void attn_kernel(
    const _Float16* __restrict__ ws16, float* __restrict__ hv,
    float* __restrict__ ha)
{
  __shared__ __align__(16) _Float16 smem[55552];   // ~108.5 KB
  _Float16* Kl = smem;            // [256 rows][8 chunks]  32 KB
  _Float16* Vl = smem + 16384;    // [64 rows][32 chunks]  32 KB
  _Float16* Ql = smem + 32768;    // [64 rows][8 chunks]    8 KB
  _Float16* P  = smem + 36864;    // [64 rows][32 chunks]  32 KB
  float* m_s  = (float*)(smem + 53248);   // [8][64]
  float* l_s  = m_s + 512;                // [8][64]
  float* Mtot = l_s + 512;                // [64]
  float* Ltot = Mtot + 64;                // [64]

  const int x = blockIdx.x;       // bh*2 + side
  const int side = x & 1;
  const int bh = x >> 1;
  const int b = bh >> 3, h = bh & 7;

  const int tid = threadIdx.x;
  const int w = tid >> 6;         // wave 0..7
  const int lane = tid & 63;
  const int l15 = lane & 15;
  const int kg = lane >> 4;       // 0..3

  const _Float16* gQ = ws16 + OQ16 + (size_t)bh * 4096;
  const _Float16* gK = ws16 + OK16 + (size_t)side * SIDESZ + (size_t)bh * 16384;
  const _Float16* gV = ws16 + OVT16 + (size_t)side * SIDESZ + (size_t)bh * 16384;

  // ---- coalesced staging (16B/lane contiguous) with XOR chunk swizzle
  {
    int ch = tid;                 // Q: 512 chunks (8 per row)
    int row = ch >> 3, c = ch & 7;
    *reinterpret_cast<f16x8*>(&Ql[row * 64 + ((c ^ (row & 7)) * 8)]) =
        *reinterpret_cast<const f16x8*>(&gQ[ch * 8]);
  }
  #pragma unroll
  for (int i = 0; i < 4; ++i) {   // K: 2048 chunks (8 per row)
    int ch = tid + i * 512;
    int row = ch >> 3, c = ch & 7;
    *reinterpret_cast<f16x8*>(&Kl[row * 64 + ((c ^ (row & 7)) * 8)]) =
        *reinterpret_cast<const f16x8*>(&gK[ch * 8]);
  }
  #pragma unroll
  for (int i = 0; i < 4; ++i) {   // VT: 2048 chunks (32 per row)
    int ch = tid + i * 512;
    int row = ch >> 5, c = ch & 31;
    *reinterpret_cast<f16x8*>(&Vl[row * 256 + ((c ^ (row & 7)) * 8)]) =
        *reinterpret_cast<const f16x8*>(&gV[ch * 8]);
  }
  __syncthreads();

  // ---- QK^T: S^T[key][q] = mfma(K,Q), keys w*32 + kf*16 + l15
  f16x8 qb[4][2];
  #pragma unroll
  for (int qf = 0; qf < 4; ++qf)
    #pragma unroll
    for (int ks = 0; ks < 2; ++ks)
      qb[qf][ks] = *reinterpret_cast<const f16x8*>(
          &Ql[(qf * 16 + l15) * 64 + (((ks * 4 + kg) ^ (l15 & 7)) * 8)]);

  f32x4 st[2][4] = {};
  #pragma unroll
  for (int kf = 0; kf < 2; ++kf) {
    int krow = w * 32 + kf * 16 + l15;
    #pragma unroll
    for (int ks = 0; ks < 2; ++ks) {
      f16x8 af = *reinterpret_cast<const f16x8*>(
          &Kl[krow * 64 + (((ks * 4 + kg) ^ (l15 & 7)) * 8)]);
      #pragma unroll
      for (int qf = 0; qf < 4; ++qf)
        st[kf][qf] = __builtin_amdgcn_mfma_f32_16x16x32_f16(
            af, qb[qf][ks], st[kf][qf], 0, 0, 0);
    }
  }
  // st[kf][qf][r] = S[key=w*32+kf*16+4*kg+r][q=qf*16+l15]

  // ---- per-wave max (32 keys) -> LDS -> global max over 8 waves
  float mx[4];
  #pragma unroll
  for (int qf = 0; qf < 4; ++qf) {
    float m = st[0][qf][0];
    #pragma unroll
    for (int kf = 0; kf < 2; ++kf)
      #pragma unroll
      for (int r = 0; r < 4; ++r) m = fmaxf(m, st[kf][qf][r]);
    m = fmaxf(m, __shfl_xor(m, 16));
    m = fmaxf(m, __shfl_xor(m, 32));
    mx[qf] = m;
  }
  if (kg == 0) {
    #pragma unroll
    for (int qf = 0; qf < 4; ++qf) m_s[w * 64 + qf * 16 + l15] = mx[qf];
  }
  __syncthreads();
  if (tid < 64) {
    float M = m_s[tid];
    #pragma unroll
    for (int w2 = 1; w2 < 8; ++w2) M = fmaxf(M, m_s[w2 * 64 + tid]);
    Mtot[tid] = M;
  }
  __syncthreads();

  // ---- exp, partial sums, P -> swizzled LDS
  #pragma unroll
  for (int qf = 0; qf < 4; ++qf) {
    float M = Mtot[qf * 16 + l15];
    float ls = 0.f;
    #pragma unroll
    for (int kf = 0; kf < 2; ++kf)
      #pragma unroll
      for (int r = 0; r < 4; ++r) {
        float e = __expf(st[kf][qf][r] - M);
        st[kf][qf][r] = e;
        ls += e;
      }
    ls += __shfl_xor(ls, 16);
    ls += __shfl_xor(ls, 32);
    if (kg == 0) l_s[w * 64 + qf * 16 + l15] = ls;
    #pragma unroll
    for (int kf = 0; kf < 2; ++kf) {
      int q = qf * 16 + l15;
      int chunk = w * 4 + kf * 2 + (kg >> 1);
      f16x4 pk = {(_Float16)st[kf][qf][0], (_Float16)st[kf][qf][1],
                  (_Float16)st[kf][qf][2], (_Float16)st[kf][qf][3]};
      *reinterpret_cast<f16x4*>(
          &P[q * 256 + ((chunk ^ (q & 7)) * 8) + (kg & 1) * 4]) = pk;
    }
  }
  __syncthreads();
  if (tid < 64) {
    float L = l_s[tid];
    #pragma unroll
    for (int w2 = 1; w2 < 8; ++w2) L += l_s[w2 * 64 + tid];
    Ltot[tid] = L;
  }
  __syncthreads();

  // ---- PV: wave owns (qf = w&3, d-frags 2*(w>>2)+{0,1}), all 256 keys
  const int qf = w & 3;
  const int d0 = (w >> 2) * 2;
  f32x4 oc[2] = {};
  #pragma unroll
  for (int ks = 0; ks < 8; ++ks) {
    f16x8 pa = *reinterpret_cast<const f16x8*>(
        &P[(qf * 16 + l15) * 256 + (((ks * 4 + kg) ^ (l15 & 7)) * 8)]);
    #pragma unroll
    for (int j = 0; j < 2; ++j) {
      int d = (d0 + j) * 16 + l15;
      f16x8 vb = *reinterpret_cast<const f16x8*>(
          &Vl[d * 256 + (((ks * 4 + kg) ^ (d & 7)) * 8)]);
      oc[j] = __builtin_amdgcn_mfma_f32_16x16x32_f16(pa, vb, oc[j], 0, 0, 0);
    }
  }

  float* houtS = side ? ha : hv;
  #pragma unroll
  for (int j = 0; j < 2; ++j)
    #pragma unroll
    for (int r = 0; r < 4; ++r) {
      int q = qf * 16 + kg * 4 + r;
      int d = (d0 + j) * 16 + l15;
      houtS[(size_t)(b * 64 + q) * 512 + h * 64 + d] =
          oc[j][r] * (1.0f / Ltot[q]);
    }
}

extern "C" void kernel_launch(void* const* d_in, const int* in_sizes, int n_in,
                              void* d_out, int out_size, void* d_ws, size_t ws_size,
                              hipStream_t stream) {
  const float* xmm   = (const float*)d_in[0];  // [2,64,512]
  const float* xa    = (const float*)d_in[1];  // [2,256,512]
  const float* xv    = (const float*)d_in[2];  // [2,256,512]
  const float* Wq    = (const float*)d_in[3];  // [512,512]
  const float* Wkv   = (const float*)d_in[4];  // [1024,1024]
  const float* Wproj = (const float*)d_in[5];  // [512,512]
  const float* bproj = (const float*)d_in[6];  // [512]
  float* out = (float*)d_out;                  // [2,64,512]
  _Float16* ws16 = (_Float16*)d_ws;
  float* hv = (float*)(ws16 + OHOUT16);
  float* ha = hv + 65536;

  fused_proj_kernel<<<272, 256, 0, stream>>>(xmm, xa, xv, Wq, Wkv, ws16);
  attn_kernel<<<32, 512, 0, stream>>>(ws16, hv, ha);
  proj_out_kernel<<<16, 256, 0, stream>>>(ws16, Wproj, bproj, out);
}